// Round 2
// baseline (470.086 us; speedup 1.0000x reference)
//
#include <hip/hip_runtime.h>
#include <hip/hip_bf16.h>

// StateSpaceMixer MI355X — round 2: 256x256 8-phase GEMMs (T2+T3+T4+T5).
// B=4 T=4096 D=1024 S=2048 K=4. bf16 MFMA, fp32 accumulate.
//
// Workspace layout (<= 172 MiB):
//   [0,64M)    mixed bf16 [16384][2048]   (reused as z fp32 [16384][1024] after conv)
//   [64M,128M) h     bf16 [16384][2048]
//   [128M,160M) xb   bf16 [16384][1024]
//   [160M,168M) W_inT bf16 [4096][1024]  (rows PERMUTED: mixed/gate 16-col interleave)
//   [168M,172M) W_outT bf16 [1024][2048]

#define Bdim 4
#define Tdim 4096
#define Ddim 1024
#define Sdim 2048
#define Mdim (Bdim * Tdim)   // 16384
#define LN_EPS 1e-5f

typedef __bf16 bf16;
typedef __bf16 bf16x8 __attribute__((ext_vector_type(8)));
typedef float f32x4 __attribute__((ext_vector_type(4)));

#define BAR() __builtin_amdgcn_s_barrier()
#define SCHED() __builtin_amdgcn_sched_barrier(0)
#define LGKM0() asm volatile("s_waitcnt lgkmcnt(0)" ::: "memory")
#define VMCNT4() asm volatile("s_waitcnt vmcnt(4)" ::: "memory")
#define VMCNT0() asm volatile("s_waitcnt vmcnt(0)" ::: "memory")

__device__ __forceinline__ void gload_lds16(const bf16* g, bf16* l) {
  __builtin_amdgcn_global_load_lds((const __attribute__((address_space(1))) void*)g,
                                   (__attribute__((address_space(3))) void*)l,
                                   16, 0, 0);
}

__device__ __forceinline__ f32x4 zero4() {
  f32x4 z; z[0] = 0.f; z[1] = 0.f; z[2] = 0.f; z[3] = 0.f; return z;
}

// ---------------- Pass 0a: cast x fp32 -> bf16 ----------------
__global__ __launch_bounds__(256) void k_cast_x(const float* __restrict__ x,
                                                bf16* __restrict__ xb) {
  int gid = blockIdx.x * 256 + threadIdx.x;
  const float4* p = (const float4*)x + (size_t)gid * 2;
  float4 a = p[0], b = p[1];
  bf16x8 o;
  o[0] = (bf16)a.x; o[1] = (bf16)a.y; o[2] = (bf16)a.z; o[3] = (bf16)a.w;
  o[4] = (bf16)b.x; o[5] = (bf16)b.y; o[6] = (bf16)b.z; o[7] = (bf16)b.w;
  ((bf16x8*)xb)[gid] = o;
}

// ---------------- Pass 0b: transpose + cast (+ optional gate-interleave perm) --
// out[perm(c)][r] = (bf16) in[r][c];  in: [R? no: [RxC]] fp32; out: [C][R] bf16
// perm (permmode=1, C=4096): c<2048 -> (c>>4)*32+(c&15); else u=c-2048 -> (u>>4)*32+16+(u&15)
__global__ __launch_bounds__(256) void k_transpose_cast(const float* __restrict__ in,
                                                        bf16* __restrict__ out,
                                                        int R, int C, int permmode) {
  __shared__ float tile[32][33];
  int tx = threadIdx.x & 31;
  int ty = threadIdx.x >> 5;           // 0..7
  int r0 = blockIdx.y * 32;
  int c0 = blockIdx.x * 32;
#pragma unroll
  for (int i = 0; i < 4; ++i)
    tile[ty + i * 8][tx] = in[(size_t)(r0 + ty + i * 8) * C + c0 + tx];
  __syncthreads();
#pragma unroll
  for (int i = 0; i < 4; ++i) {
    int oc = c0 + ty + i * 8;
    int pr = oc;
    if (permmode) {
      pr = (oc < 2048) ? ((oc >> 4) * 32 + (oc & 15))
                       : (((oc - 2048) >> 4) * 32 + 16 + (oc & 15));
    }
    out[(size_t)pr * R + r0 + tx] = (bf16)tile[tx][ty + i * 8];
  }
}

// ---------------- 256x256 8-phase GEMM (m201-style, derived waits) ----------
// A [M][KTOT] bf16 row-major, Bg [N][KTOT] bf16 row-major (B^T form).
// LDS per slot (64KB): A0@0, A1@16K, B0@32K, B1@48K; slot1 at +64K. st_16x32 swizzle.
// EPI 0: gated epilogue (permuted-col pairing) -> outb bf16 [M][2048]
// EPI 1: residual epilogue -> outf fp32 [M][1024], xres = x
template<int KTOT, int NTN, int EPI>
__global__ __launch_bounds__(512, 1)
void k_gemm256(const bf16* __restrict__ Ag, const bf16* __restrict__ Bg,
               const float* __restrict__ bias, const float* __restrict__ xres,
               bf16* __restrict__ outb, float* __restrict__ outf) {
  __shared__ __attribute__((aligned(16))) char lds[131072];

  const int tid = threadIdx.x;
  const int w = tid >> 6, lane = tid & 63;
  const int lr = lane & 15, lk = lane >> 4;
  const int wr = w >> 2, wc = w & 3;        // 2 x 4 wave grid

  const int nwg = gridDim.x;
  const int bid = blockIdx.x;
  const int wg = (bid & 7) * (nwg >> 3) + (bid >> 3);   // XCD swizzle (nwg%8==0)
  const int m0 = (wg / NTN) * 256;
  const int n0 = (wg % NTN) * 256;

  // writer-side (stage) per-thread constants: linear LDS dest -> logical src
  const int lsw = (lane * 16) ^ (((lane >> 5) & 1) << 5);
  const int rw = lsw >> 7;            // row within 8-row chunk
  const int cw = (lsw & 127) >> 1;    // elem col 0..63 (16B aligned)

  // reader-side swizzled base offsets (bit9 of frag addr == (lr>>2)&1)
  const int xorm = ((lr >> 2) & 1) << 5;
  const int aoff = (lr * 128 + lk * 16) ^ xorm;                        // + mi*2048 + ks*64
  const int boff = ((((wc & 1) * 64 + lr) * 128) + lk * 16) ^ xorm;    // + nj*2048 + ks*64
  const char* ldsA = lds + wr * 16384;                 // + slot*65536
  const char* ldsB = lds + 32768 + (wc >> 1) * 16384;  // + slot*65536

  auto stage = [&](const bf16* G, int row0, int kt, int regionByte) {
#pragma unroll
    for (int L = 0; L < 2; ++L) {
      int q = w * 2 + L;
      const bf16* src = G + (size_t)(row0 + q * 8 + rw) * KTOT + kt * 64 + cw;
      gload_lds16(src, (bf16*)(lds + regionByte + q * 1024));
    }
  };
  auto rdA = [&](int s, int mi, int ks) -> bf16x8 {
    return *(const bf16x8*)(ldsA + s * 65536 + mi * 2048 + ks * 64 + aoff);
  };
  auto rdB = [&](int s, int nj, int ks) -> bf16x8 {
    return *(const bf16x8*)(ldsB + s * 65536 + nj * 2048 + ks * 64 + boff);
  };

  f32x4 acc[8][4];
#pragma unroll
  for (int i = 0; i < 8; ++i)
#pragma unroll
    for (int j = 0; j < 4; ++j) acc[i][j] = zero4();

  bf16x8 a[4][2], b[4][2];

#define QUAD(rh, ch)                                                                   \
  {                                                                                    \
    _Pragma("unroll")                                                                  \
    for (int mi = 0; mi < 4; ++mi) {                                                   \
      _Pragma("unroll")                                                                \
      for (int nj = 0; nj < 2; ++nj) {                                                 \
        acc[(rh)*4+mi][(ch)*2+nj] = __builtin_amdgcn_mfma_f32_16x16x32_bf16(           \
            a[mi][0], b[(ch)*2+nj][0], acc[(rh)*4+mi][(ch)*2+nj], 0, 0, 0);            \
        acc[(rh)*4+mi][(ch)*2+nj] = __builtin_amdgcn_mfma_f32_16x16x32_bf16(           \
            a[mi][1], b[(ch)*2+nj][1], acc[(rh)*4+mi][(ch)*2+nj], 0, 0, 0);            \
      }                                                                                \
    }                                                                                  \
  }

  const int NI = KTOT / 128;

  // ---- prologue: tile0 all 4 halves, tile1 B halves; allow tile1-B in flight
  stage(Bg, n0,       0, 32768);
  stage(Bg, n0 + 128, 0, 32768 + 16384);
  stage(Ag, m0,       0, 0);
  stage(Ag, m0 + 128, 0, 16384);
  stage(Bg, n0,       1, 65536 + 32768);
  stage(Bg, n0 + 128, 1, 65536 + 32768 + 16384);
  VMCNT4(); SCHED(); BAR(); SCHED();

  for (int i = 0; i < NI; ++i) {
    const int kta2 = 2 * i + 2;   // next even tile -> slot0
    const int ktb  = 2 * i + 1;   // this odd tile  -> slot1
    const bool nl = (i < NI - 1);

    // ---- P1: read A(rh0),B(c0) of even tile (slot0); stage b:A0
#pragma unroll
    for (int mi = 0; mi < 4; ++mi) { a[mi][0] = rdA(0, mi, 0); a[mi][1] = rdA(0, mi, 1); }
#pragma unroll
    for (int nj = 0; nj < 2; ++nj) { b[nj][0] = rdB(0, nj, 0); b[nj][1] = rdB(0, nj, 1); }
    stage(Ag, m0, ktb, 65536);
    asm volatile("s_waitcnt lgkmcnt(8)" ::: "memory");
    SCHED(); BAR(); LGKM0(); SCHED();
    __builtin_amdgcn_s_setprio(1); QUAD(0, 0); __builtin_amdgcn_s_setprio(0);
    SCHED(); BAR(); SCHED();

    // ---- P2: read B(c1); stage b:A1
#pragma unroll
    for (int nj = 0; nj < 2; ++nj) { b[2+nj][0] = rdB(0, 2+nj, 0); b[2+nj][1] = rdB(0, 2+nj, 1); }
    stage(Ag, m0 + 128, ktb, 65536 + 16384);
    SCHED(); BAR(); LGKM0(); SCHED();
    __builtin_amdgcn_s_setprio(1); QUAD(0, 1); __builtin_amdgcn_s_setprio(0);
    SCHED(); BAR(); SCHED();

    // ---- P3: read A(rh1); stage a':B0
#pragma unroll
    for (int mi = 0; mi < 4; ++mi) { a[mi][0] = rdA(0, 4+mi, 0); a[mi][1] = rdA(0, 4+mi, 1); }
    if (nl) stage(Bg, n0, kta2, 32768);
    SCHED(); BAR(); LGKM0(); SCHED();
    __builtin_amdgcn_s_setprio(1); QUAD(1, 0); __builtin_amdgcn_s_setprio(0);
    SCHED(); BAR(); SCHED();

    // ---- P4: stage a':B1; counted vmcnt (odd tile's A-halves guaranteed landed)
    if (nl) stage(Bg, n0 + 128, kta2, 32768 + 16384);
    SCHED(); BAR(); LGKM0(); SCHED();
    __builtin_amdgcn_s_setprio(1); QUAD(1, 1); __builtin_amdgcn_s_setprio(0);
    if (nl) { VMCNT4(); } else { VMCNT0(); }
    SCHED(); BAR(); SCHED();

    // ---- P5: read A(rh0),B(c0) of odd tile (slot1); stage a':A0
#pragma unroll
    for (int mi = 0; mi < 4; ++mi) { a[mi][0] = rdA(1, mi, 0); a[mi][1] = rdA(1, mi, 1); }
#pragma unroll
    for (int nj = 0; nj < 2; ++nj) { b[nj][0] = rdB(1, nj, 0); b[nj][1] = rdB(1, nj, 1); }
    if (nl) stage(Ag, m0, kta2, 0);
    asm volatile("s_waitcnt lgkmcnt(8)" ::: "memory");
    SCHED(); BAR(); LGKM0(); SCHED();
    __builtin_amdgcn_s_setprio(1); QUAD(0, 0); __builtin_amdgcn_s_setprio(0);
    SCHED(); BAR(); SCHED();

    // ---- P6: read B(c1); stage a':A1
#pragma unroll
    for (int nj = 0; nj < 2; ++nj) { b[2+nj][0] = rdB(1, 2+nj, 0); b[2+nj][1] = rdB(1, 2+nj, 1); }
    if (nl) stage(Ag, m0 + 128, kta2, 16384);
    SCHED(); BAR(); LGKM0(); SCHED();
    __builtin_amdgcn_s_setprio(1); QUAD(0, 1); __builtin_amdgcn_s_setprio(0);
    SCHED(); BAR(); SCHED();

    // ---- P7: read A(rh1); stage b':B0
#pragma unroll
    for (int mi = 0; mi < 4; ++mi) { a[mi][0] = rdA(1, 4+mi, 0); a[mi][1] = rdA(1, 4+mi, 1); }
    if (nl) stage(Bg, n0, ktb + 2, 65536 + 32768);
    SCHED(); BAR(); LGKM0(); SCHED();
    __builtin_amdgcn_s_setprio(1); QUAD(1, 0); __builtin_amdgcn_s_setprio(0);
    SCHED(); BAR(); SCHED();

    // ---- P8: stage b':B1; counted vmcnt (next even tile fully landed)
    if (nl) stage(Bg, n0 + 128, ktb + 2, 65536 + 32768 + 16384);
    SCHED(); BAR(); LGKM0(); SCHED();
    __builtin_amdgcn_s_setprio(1); QUAD(1, 1); __builtin_amdgcn_s_setprio(0);
    if (nl) { VMCNT4(); }
    SCHED(); BAR(); SCHED();
  }
#undef QUAD

  // ---- epilogue (no LDS) ----
  if (EPI == 0) {
    // permuted cols: pair (nj=2p, 2p+1) -> same lanes hold (mixed, gate) for col g*16+lr
#pragma unroll
    for (int p = 0; p < 2; ++p) {
      const int g = (n0 + wc * 64 + p * 32) >> 5;
      const int mcol = g * 16 + lr;
      const float bm = bias[mcol];
      const float bg = bias[mcol + 2048];
#pragma unroll
      for (int mi = 0; mi < 8; ++mi)
#pragma unroll
        for (int ii = 0; ii < 4; ++ii) {
          const int row = m0 + wr * 128 + mi * 16 + lk * 4 + ii;
          const float pm = acc[mi][2 * p][ii] + bm;
          const float pg = acc[mi][2 * p + 1][ii] + bg;
          outb[(size_t)row * Sdim + mcol] = (bf16)(pm / (1.0f + __expf(-pg)));
        }
    }
  } else {
#pragma unroll
    for (int nj = 0; nj < 4; ++nj) {
      const int col = n0 + wc * 64 + nj * 16 + lr;
      const float bo = bias[col];
#pragma unroll
      for (int mi = 0; mi < 8; ++mi)
#pragma unroll
        for (int ii = 0; ii < 4; ++ii) {
          const int row = m0 + wr * 128 + mi * 16 + lk * 4 + ii;
          const size_t idx = (size_t)row * Ddim + col;
          outf[idx] = xres[idx] + bo + acc[mi][nj][ii];
        }
    }
  }
}

// ---------------- Pass 2: depthwise causal conv K=4 ----------------
__global__ __launch_bounds__(256) void k_conv(const bf16* __restrict__ mixed,
                                              const float* __restrict__ cw,
                                              const float* __restrict__ cb,
                                              bf16* __restrict__ h) {
  int gid = blockIdx.x * 256 + threadIdx.x;
  int cg = gid & 255;            // channel group (8 ch)
  int tg = (gid >> 8) & 511;     // t group (8 t)
  int bb = gid >> 17;
  int ch0 = cg * 8;
  int t0 = tg * 8;
  const size_t base = ((size_t)bb * Tdim) * Sdim + ch0;

  float4 w4[8];
  float bias[8];
#pragma unroll
  for (int j = 0; j < 8; ++j) {
    w4[j] = ((const float4*)cw)[ch0 + j];
    bias[j] = cb[ch0 + j];
  }

  bf16x8 zv;
#pragma unroll
  for (int j = 0; j < 8; ++j) zv[j] = (bf16)0.0f;

  bf16x8 win[11];
#pragma unroll
  for (int i = 0; i < 11; ++i) {
    int t = t0 - 3 + i;
    win[i] = (t >= 0) ? *(const bf16x8*)(mixed + base + (size_t)t * Sdim) : zv;
  }

#pragma unroll
  for (int i = 0; i < 8; ++i) {
    bf16x8 o;
#pragma unroll
    for (int j = 0; j < 8; ++j) {
      float aa = bias[j]
              + w4[j].x * (float)win[i + 0][j]
              + w4[j].y * (float)win[i + 1][j]
              + w4[j].z * (float)win[i + 2][j]
              + w4[j].w * (float)win[i + 3][j];
      o[j] = (bf16)aa;
    }
    *(bf16x8*)(h + base + (size_t)(t0 + i) * Sdim) = o;
  }
}

// ---------------- Pass 4: LayerNorm over D=1024 ----------------
__global__ __launch_bounds__(256) void k_ln(const float* __restrict__ z,
                                            const float* __restrict__ gamma,
                                            const float* __restrict__ beta,
                                            float* __restrict__ out) {
  int row = blockIdx.x;
  int tid = threadIdx.x;
  const float4* zr = (const float4*)(z + (size_t)row * Ddim);
  float4 v = zr[tid];
  float s = v.x + v.y + v.z + v.w;
  float ss = v.x * v.x + v.y * v.y + v.z * v.z + v.w * v.w;
#pragma unroll
  for (int off = 32; off > 0; off >>= 1) {
    s += __shfl_xor(s, off);
    ss += __shfl_xor(ss, off);
  }
  __shared__ float ps[4], pss[4];
  int wave = tid >> 6, lane = tid & 63;
  if (lane == 0) { ps[wave] = s; pss[wave] = ss; }
  __syncthreads();
  float tots = ps[0] + ps[1] + ps[2] + ps[3];
  float totss = pss[0] + pss[1] + pss[2] + pss[3];
  float mu = tots * (1.0f / (float)Ddim);
  float var = totss * (1.0f / (float)Ddim) - mu * mu;
  float rs = rsqrtf(var + LN_EPS);
  float4 gg = ((const float4*)gamma)[tid];
  float4 bb = ((const float4*)beta)[tid];
  float4 o;
  o.x = (v.x - mu) * rs * gg.x + bb.x;
  o.y = (v.y - mu) * rs * gg.y + bb.y;
  o.z = (v.z - mu) * rs * gg.z + bb.z;
  o.w = (v.w - mu) * rs * gg.w + bb.w;
  ((float4*)(out + (size_t)row * Ddim))[tid] = o;
}

// ---------------- launch ----------------
extern "C" void kernel_launch(void* const* d_in, const int* in_sizes, int n_in,
                              void* d_out, int out_size, void* d_ws, size_t ws_size,
                              hipStream_t stream) {
  const float* x = (const float*)d_in[0];
  const float* W_in = (const float*)d_in[1];
  const float* b_in = (const float*)d_in[2];
  const float* conv_w = (const float*)d_in[3];
  const float* conv_b = (const float*)d_in[4];
  const float* W_out = (const float*)d_in[5];
  const float* b_out = (const float*)d_in[6];
  const float* gamma = (const float*)d_in[7];
  const float* beta = (const float*)d_in[8];
  float* out = (float*)d_out;

  char* ws = (char*)d_ws;
  bf16* mixed = (bf16*)ws;                              // 64 MiB
  bf16* hbuf = (bf16*)(ws + ((size_t)64 << 20));        // 64 MiB
  bf16* xb = (bf16*)(ws + ((size_t)128 << 20));         // 32 MiB
  bf16* winT = (bf16*)(ws + ((size_t)160 << 20));       // 8 MiB (permuted rows)
  bf16* woutT = (bf16*)(ws + ((size_t)168 << 20));      // 4 MiB
  float* z = (float*)mixed;  // mixed dead after conv

  k_cast_x<<<dim3(Mdim * Ddim / 8 / 256), dim3(256), 0, stream>>>(x, xb);
  k_transpose_cast<<<dim3(4096 / 32, 1024 / 32), dim3(256), 0, stream>>>(W_in, winT, 1024, 4096, 1);
  k_transpose_cast<<<dim3(1024 / 32, 2048 / 32), dim3(256), 0, stream>>>(W_out, woutT, 2048, 1024, 0);

  // GEMM1: [16384,4096] = xb @ winT^T, K=1024, gated epilogue -> mixed bf16
  k_gemm256<1024, 16, 0><<<dim3(Mdim / 256 * (4096 / 256)), dim3(512), 0, stream>>>(
      xb, winT, b_in, nullptr, mixed, nullptr);

  k_conv<<<dim3(Bdim * (Tdim / 8) * (Sdim / 8) / 256), dim3(256), 0, stream>>>(
      mixed, conv_w, conv_b, hbuf);

  // GEMM2: [16384,1024] = h @ woutT^T, K=2048, residual epilogue -> z fp32
  k_gemm256<2048, 4, 1><<<dim3(Mdim / 256 * (Ddim / 256)), dim3(512), 0, stream>>>(
      hbuf, woutT, b_out, x, nullptr, z);

  k_ln<<<dim3(Mdim), dim3(256), 0, stream>>>(z, gamma, beta, out);
}

// Round 5
// 462.212 us; speedup vs baseline: 1.0170x; 1.0170x over previous
//
#include <hip/hip_runtime.h>
#include <hip/hip_bf16.h>

// StateSpaceMixer MI355X — round 5 (resubmit; R3/R4 never ran: broker timeout).
// Corrected LDS swizzle (XOR bank bits 5-6 with row bits 0-1). R2's swizzle
// (bit9->bit5) left slot occupancy at 16 lanes/4 slots == linear
// (SQ_LDS_BANK_CONFLICT unchanged at 1.26e7). This swizzle balances 8 lanes
// on each of 8 16B-slots (the wave64 minimum).
//
// Workspace layout (<= 172 MiB):
//   [0,64M)    mixed bf16 [16384][2048]   (reused as z fp32 [16384][1024] after conv)
//   [64M,128M) h     bf16 [16384][2048]
//   [128M,160M) xb   bf16 [16384][1024]
//   [160M,168M) W_inT bf16 [4096][1024]  (rows PERMUTED: mixed/gate 16-col interleave)
//   [168M,172M) W_outT bf16 [1024][2048]

#define Bdim 4
#define Tdim 4096
#define Ddim 1024
#define Sdim 2048
#define Mdim (Bdim * Tdim)   // 16384
#define LN_EPS 1e-5f

typedef __bf16 bf16;
typedef __bf16 bf16x8 __attribute__((ext_vector_type(8)));
typedef float f32x4 __attribute__((ext_vector_type(4)));

#define BAR() __builtin_amdgcn_s_barrier()
#define SCHED() __builtin_amdgcn_sched_barrier(0)
#define LGKM0() asm volatile("s_waitcnt lgkmcnt(0)" ::: "memory")
#define VMCNT4() asm volatile("s_waitcnt vmcnt(4)" ::: "memory")
#define VMCNT0() asm volatile("s_waitcnt vmcnt(0)" ::: "memory")

__device__ __forceinline__ void gload_lds16(const bf16* g, bf16* l) {
  __builtin_amdgcn_global_load_lds((const __attribute__((address_space(1))) void*)g,
                                   (__attribute__((address_space(3))) void*)l,
                                   16, 0, 0);
}

__device__ __forceinline__ f32x4 zero4() {
  f32x4 z; z[0] = 0.f; z[1] = 0.f; z[2] = 0.f; z[3] = 0.f; return z;
}

// ---------------- Pass 0a: cast x fp32 -> bf16 ----------------
__global__ __launch_bounds__(256) void k_cast_x(const float* __restrict__ x,
                                                bf16* __restrict__ xb) {
  int gid = blockIdx.x * 256 + threadIdx.x;
  const float4* p = (const float4*)x + (size_t)gid * 2;
  float4 a = p[0], b = p[1];
  bf16x8 o;
  o[0] = (bf16)a.x; o[1] = (bf16)a.y; o[2] = (bf16)a.z; o[3] = (bf16)a.w;
  o[4] = (bf16)b.x; o[5] = (bf16)b.y; o[6] = (bf16)b.z; o[7] = (bf16)b.w;
  ((bf16x8*)xb)[gid] = o;
}

// ---------------- Pass 0b: transpose + cast (+ optional gate-interleave perm) --
__global__ __launch_bounds__(256) void k_transpose_cast(const float* __restrict__ in,
                                                        bf16* __restrict__ out,
                                                        int R, int C, int permmode) {
  __shared__ float tile[32][33];
  int tx = threadIdx.x & 31;
  int ty = threadIdx.x >> 5;           // 0..7
  int r0 = blockIdx.y * 32;
  int c0 = blockIdx.x * 32;
#pragma unroll
  for (int i = 0; i < 4; ++i)
    tile[ty + i * 8][tx] = in[(size_t)(r0 + ty + i * 8) * C + c0 + tx];
  __syncthreads();
#pragma unroll
  for (int i = 0; i < 4; ++i) {
    int oc = c0 + ty + i * 8;
    int pr = oc;
    if (permmode) {
      pr = (oc < 2048) ? ((oc >> 4) * 32 + (oc & 15))
                       : (((oc - 2048) >> 4) * 32 + 16 + (oc & 15));
    }
    out[(size_t)pr * R + r0 + tx] = (bf16)tile[tx][ty + i * 8];
  }
}

// ---------------- 256x256 8-phase GEMM (derived waits + corrected swizzle) ----
// A [M][KTOT] bf16 row-major, Bg [N][KTOT] bf16 row-major (B^T form).
// LDS per slot (64KB): A0@0, A1@16K, B0@32K, B1@48K; slot1 at +64K.
// Swizzle (involution, both-sides): byte' = byte ^ (((byte>>7)&3)<<5)
//   -> reader slot (4*ks+lk) ^ (2*(row&3)): 8 lanes on each of 8 slots.
// EPI 0: gated epilogue (permuted-col pairing) -> outb bf16 [M][2048]
// EPI 1: residual epilogue -> outf fp32 [M][1024], xres = x
template<int KTOT, int NTN, int EPI>
__global__ __launch_bounds__(512, 1)
void k_gemm256(const bf16* __restrict__ Ag, const bf16* __restrict__ Bg,
               const float* __restrict__ bias, const float* __restrict__ xres,
               bf16* __restrict__ outb, float* __restrict__ outf) {
  __shared__ __attribute__((aligned(16))) char lds[131072];

  const int tid = threadIdx.x;
  const int w = tid >> 6, lane = tid & 63;
  const int lr = lane & 15, lk = lane >> 4;
  const int wr = w >> 2, wc = w & 3;        // 2 x 4 wave grid

  const int nwg = gridDim.x;
  const int bid = blockIdx.x;
  const int wg = (bid & 7) * (nwg >> 3) + (bid >> 3);   // XCD swizzle (nwg%8==0)
  const int m0 = (wg / NTN) * 256;
  const int n0 = (wg % NTN) * 256;

  // writer-side: linear LDS dest d=lane*16 holds logical offset L = swz(d)
  const int dlin = lane * 16;
  const int lsw = dlin ^ (((dlin >> 7) & 3) << 5);
  const int rw = lsw >> 7;            // row within 8-row chunk
  const int cw = (lsw & 127) >> 1;    // elem col 0..63 (16B aligned)

  // reader-side: addr = row*128 + ((ks*64 + lk*16) ^ ((row&3)<<5))
  const int xmask = (lr & 3) << 5;                 // row&3 == lr&3 for both A,B
  const int arow = lr * 128;
  const int brow = ((wc & 1) * 64 + lr) * 128;
  const char* ldsA = lds + wr * 16384;                 // + slot*65536
  const char* ldsB = lds + 32768 + (wc >> 1) * 16384;  // + slot*65536

  auto stage = [&](const bf16* G, int row0, int kt, int regionByte) {
#pragma unroll
    for (int L = 0; L < 2; ++L) {
      int q = w * 2 + L;
      const bf16* src = G + (size_t)(row0 + q * 8 + rw) * KTOT + kt * 64 + cw;
      gload_lds16(src, (bf16*)(lds + regionByte + q * 1024));
    }
  };
  auto rdA = [&](int s, int mi, int ks) -> bf16x8 {
    return *(const bf16x8*)(ldsA + s * 65536 + mi * 2048 + arow +
                            ((ks * 64 + lk * 16) ^ xmask));
  };
  auto rdB = [&](int s, int nj, int ks) -> bf16x8 {
    return *(const bf16x8*)(ldsB + s * 65536 + nj * 2048 + brow +
                            ((ks * 64 + lk * 16) ^ xmask));
  };

  f32x4 acc[8][4];
#pragma unroll
  for (int i = 0; i < 8; ++i)
#pragma unroll
    for (int j = 0; j < 4; ++j) acc[i][j] = zero4();

  bf16x8 a[4][2], b[4][2];

#define QUAD(rh, ch)                                                                   \
  {                                                                                    \
    _Pragma("unroll")                                                                  \
    for (int mi = 0; mi < 4; ++mi) {                                                   \
      _Pragma("unroll")                                                                \
      for (int nj = 0; nj < 2; ++nj) {                                                 \
        acc[(rh)*4+mi][(ch)*2+nj] = __builtin_amdgcn_mfma_f32_16x16x32_bf16(           \
            a[mi][0], b[(ch)*2+nj][0], acc[(rh)*4+mi][(ch)*2+nj], 0, 0, 0);            \
        acc[(rh)*4+mi][(ch)*2+nj] = __builtin_amdgcn_mfma_f32_16x16x32_bf16(           \
            a[mi][1], b[(ch)*2+nj][1], acc[(rh)*4+mi][(ch)*2+nj], 0, 0, 0);            \
      }                                                                                \
    }                                                                                  \
  }

  const int NI = KTOT / 128;

  // ---- prologue: tile0 all 4 halves, tile1 B halves; allow tile1-B in flight
  stage(Bg, n0,       0, 32768);
  stage(Bg, n0 + 128, 0, 32768 + 16384);
  stage(Ag, m0,       0, 0);
  stage(Ag, m0 + 128, 0, 16384);
  stage(Bg, n0,       1, 65536 + 32768);
  stage(Bg, n0 + 128, 1, 65536 + 32768 + 16384);
  VMCNT4(); SCHED(); BAR(); SCHED();

  for (int i = 0; i < NI; ++i) {
    const int kta2 = 2 * i + 2;   // next even tile -> slot0
    const int ktb  = 2 * i + 1;   // this odd tile  -> slot1
    const bool nl = (i < NI - 1);

    // ---- P1: read A(rh0),B(c0) of even tile (slot0); stage b:A0
#pragma unroll
    for (int mi = 0; mi < 4; ++mi) { a[mi][0] = rdA(0, mi, 0); a[mi][1] = rdA(0, mi, 1); }
#pragma unroll
    for (int nj = 0; nj < 2; ++nj) { b[nj][0] = rdB(0, nj, 0); b[nj][1] = rdB(0, nj, 1); }
    stage(Ag, m0, ktb, 65536);
    asm volatile("s_waitcnt lgkmcnt(8)" ::: "memory");
    SCHED(); BAR(); LGKM0(); SCHED();
    __builtin_amdgcn_s_setprio(1); QUAD(0, 0); __builtin_amdgcn_s_setprio(0);
    SCHED(); BAR(); SCHED();

    // ---- P2: read B(c1); stage b:A1
#pragma unroll
    for (int nj = 0; nj < 2; ++nj) { b[2+nj][0] = rdB(0, 2+nj, 0); b[2+nj][1] = rdB(0, 2+nj, 1); }
    stage(Ag, m0 + 128, ktb, 65536 + 16384);
    SCHED(); BAR(); LGKM0(); SCHED();
    __builtin_amdgcn_s_setprio(1); QUAD(0, 1); __builtin_amdgcn_s_setprio(0);
    SCHED(); BAR(); SCHED();

    // ---- P3: read A(rh1); stage a':B0
#pragma unroll
    for (int mi = 0; mi < 4; ++mi) { a[mi][0] = rdA(0, 4+mi, 0); a[mi][1] = rdA(0, 4+mi, 1); }
    if (nl) stage(Bg, n0, kta2, 32768);
    SCHED(); BAR(); LGKM0(); SCHED();
    __builtin_amdgcn_s_setprio(1); QUAD(1, 0); __builtin_amdgcn_s_setprio(0);
    SCHED(); BAR(); SCHED();

    // ---- P4: stage a':B1; counted vmcnt (odd tile's A-halves guaranteed landed)
    if (nl) stage(Bg, n0 + 128, kta2, 32768 + 16384);
    SCHED(); BAR(); LGKM0(); SCHED();
    __builtin_amdgcn_s_setprio(1); QUAD(1, 1); __builtin_amdgcn_s_setprio(0);
    if (nl) { VMCNT4(); } else { VMCNT0(); }
    SCHED(); BAR(); SCHED();

    // ---- P5: read A(rh0),B(c0) of odd tile (slot1); stage a':A0
#pragma unroll
    for (int mi = 0; mi < 4; ++mi) { a[mi][0] = rdA(1, mi, 0); a[mi][1] = rdA(1, mi, 1); }
#pragma unroll
    for (int nj = 0; nj < 2; ++nj) { b[nj][0] = rdB(1, nj, 0); b[nj][1] = rdB(1, nj, 1); }
    if (nl) stage(Ag, m0, kta2, 0);
    asm volatile("s_waitcnt lgkmcnt(8)" ::: "memory");
    SCHED(); BAR(); LGKM0(); SCHED();
    __builtin_amdgcn_s_setprio(1); QUAD(0, 0); __builtin_amdgcn_s_setprio(0);
    SCHED(); BAR(); SCHED();

    // ---- P6: read B(c1); stage a':A1
#pragma unroll
    for (int nj = 0; nj < 2; ++nj) { b[2+nj][0] = rdB(1, 2+nj, 0); b[2+nj][1] = rdB(1, 2+nj, 1); }
    if (nl) stage(Ag, m0 + 128, kta2, 16384);
    SCHED(); BAR(); LGKM0(); SCHED();
    __builtin_amdgcn_s_setprio(1); QUAD(0, 1); __builtin_amdgcn_s_setprio(0);
    SCHED(); BAR(); SCHED();

    // ---- P7: read A(rh1); stage b':B0
#pragma unroll
    for (int mi = 0; mi < 4; ++mi) { a[mi][0] = rdA(1, 4+mi, 0); a[mi][1] = rdA(1, 4+mi, 1); }
    if (nl) stage(Bg, n0, ktb + 2, 65536 + 32768);
    SCHED(); BAR(); LGKM0(); SCHED();
    __builtin_amdgcn_s_setprio(1); QUAD(1, 0); __builtin_amdgcn_s_setprio(0);
    SCHED(); BAR(); SCHED();

    // ---- P8: stage b':B1; counted vmcnt (next even tile fully landed)
    if (nl) stage(Bg, n0 + 128, ktb + 2, 65536 + 32768 + 16384);
    SCHED(); BAR(); LGKM0(); SCHED();
    __builtin_amdgcn_s_setprio(1); QUAD(1, 1); __builtin_amdgcn_s_setprio(0);
    if (nl) { VMCNT4(); }
    SCHED(); BAR(); SCHED();
  }
#undef QUAD

  // ---- epilogue (no LDS) ----
  if (EPI == 0) {
#pragma unroll
    for (int p = 0; p < 2; ++p) {
      const int g = (n0 + wc * 64 + p * 32) >> 5;
      const int mcol = g * 16 + lr;
      const float bm = bias[mcol];
      const float bg = bias[mcol + 2048];
#pragma unroll
      for (int mi = 0; mi < 8; ++mi)
#pragma unroll
        for (int ii = 0; ii < 4; ++ii) {
          const int row = m0 + wr * 128 + mi * 16 + lk * 4 + ii;
          const float pm = acc[mi][2 * p][ii] + bm;
          const float pg = acc[mi][2 * p + 1][ii] + bg;
          outb[(size_t)row * Sdim + mcol] = (bf16)(pm / (1.0f + __expf(-pg)));
        }
    }
  } else {
#pragma unroll
    for (int nj = 0; nj < 4; ++nj) {
      const int col = n0 + wc * 64 + nj * 16 + lr;
      const float bo = bias[col];
#pragma unroll
      for (int mi = 0; mi < 8; ++mi)
#pragma unroll
        for (int ii = 0; ii < 4; ++ii) {
          const int row = m0 + wr * 128 + mi * 16 + lk * 4 + ii;
          const size_t idx = (size_t)row * Ddim + col;
          outf[idx] = xres[idx] + bo + acc[mi][nj][ii];
        }
    }
  }
}

// ---------------- Pass 2: depthwise causal conv K=4 ----------------
__global__ __launch_bounds__(256) void k_conv(const bf16* __restrict__ mixed,
                                              const float* __restrict__ cw,
                                              const float* __restrict__ cb,
                                              bf16* __restrict__ h) {
  int gid = blockIdx.x * 256 + threadIdx.x;
  int cg = gid & 255;            // channel group (8 ch)
  int tg = (gid >> 8) & 511;     // t group (8 t)
  int bb = gid >> 17;
  int ch0 = cg * 8;
  int t0 = tg * 8;
  const size_t base = ((size_t)bb * Tdim) * Sdim + ch0;

  float4 w4[8];
  float bias[8];
#pragma unroll
  for (int j = 0; j < 8; ++j) {
    w4[j] = ((const float4*)cw)[ch0 + j];
    bias[j] = cb[ch0 + j];
  }

  bf16x8 zv;
#pragma unroll
  for (int j = 0; j < 8; ++j) zv[j] = (bf16)0.0f;

  bf16x8 win[11];
#pragma unroll
  for (int i = 0; i < 11; ++i) {
    int t = t0 - 3 + i;
    win[i] = (t >= 0) ? *(const bf16x8*)(mixed + base + (size_t)t * Sdim) : zv;
  }

#pragma unroll
  for (int i = 0; i < 8; ++i) {
    bf16x8 o;
#pragma unroll
    for (int j = 0; j < 8; ++j) {
      float aa = bias[j]
              + w4[j].x * (float)win[i + 0][j]
              + w4[j].y * (float)win[i + 1][j]
              + w4[j].z * (float)win[i + 2][j]
              + w4[j].w * (float)win[i + 3][j];
      o[j] = (bf16)aa;
    }
    *(bf16x8*)(h + base + (size_t)(t0 + i) * Sdim) = o;
  }
}

// ---------------- Pass 4: LayerNorm over D=1024 ----------------
__global__ __launch_bounds__(256) void k_ln(const float* __restrict__ z,
                                            const float* __restrict__ gamma,
                                            const float* __restrict__ beta,
                                            float* __restrict__ out) {
  int row = blockIdx.x;
  int tid = threadIdx.x;
  const float4* zr = (const float4*)(z + (size_t)row * Ddim);
  float4 v = zr[tid];
  float s = v.x + v.y + v.z + v.w;
  float ss = v.x * v.x + v.y * v.y + v.z * v.z + v.w * v.w;
#pragma unroll
  for (int off = 32; off > 0; off >>= 1) {
    s += __shfl_xor(s, off);
    ss += __shfl_xor(ss, off);
  }
  __shared__ float ps[4], pss[4];
  int wave = tid >> 6, lane = tid & 63;
  if (lane == 0) { ps[wave] = s; pss[wave] = ss; }
  __syncthreads();
  float tots = ps[0] + ps[1] + ps[2] + ps[3];
  float totss = pss[0] + pss[1] + pss[2] + pss[3];
  float mu = tots * (1.0f / (float)Ddim);
  float var = totss * (1.0f / (float)Ddim) - mu * mu;
  float rs = rsqrtf(var + LN_EPS);
  float4 gg = ((const float4*)gamma)[tid];
  float4 bb = ((const float4*)beta)[tid];
  float4 o;
  o.x = (v.x - mu) * rs * gg.x + bb.x;
  o.y = (v.y - mu) * rs * gg.y + bb.y;
  o.z = (v.z - mu) * rs * gg.z + bb.z;
  o.w = (v.w - mu) * rs * gg.w + bb.w;
  ((float4*)(out + (size_t)row * Ddim))[tid] = o;
}

// ---------------- launch ----------------
extern "C" void kernel_launch(void* const* d_in, const int* in_sizes, int n_in,
                              void* d_out, int out_size, void* d_ws, size_t ws_size,
                              hipStream_t stream) {
  const float* x = (const float*)d_in[0];
  const float* W_in = (const float*)d_in[1];
  const float* b_in = (const float*)d_in[2];
  const float* conv_w = (const float*)d_in[3];
  const float* conv_b = (const float*)d_in[4];
  const float* W_out = (const float*)d_in[5];
  const float* b_out = (const float*)d_in[6];
  const float* gamma = (const float*)d_in[7];
  const float* beta = (const float*)d_in[8];
  float* out = (float*)d_out;

  char* ws = (char*)d_ws;
  bf16* mixed = (bf16*)ws;                              // 64 MiB
  bf16* hbuf = (bf16*)(ws + ((size_t)64 << 20));        // 64 MiB
  bf16* xb = (bf16*)(ws + ((size_t)128 << 20));         // 32 MiB
  bf16* winT = (bf16*)(ws + ((size_t)160 << 20));       // 8 MiB (permuted rows)
  bf16* woutT = (bf16*)(ws + ((size_t)168 << 20));      // 4 MiB
  float* z = (float*)mixed;  // mixed dead after conv

  k_cast_x<<<dim3(Mdim * Ddim / 8 / 256), dim3(256), 0, stream>>>(x, xb);
  k_transpose_cast<<<dim3(4096 / 32, 1024 / 32), dim3(256), 0, stream>>>(W_in, winT, 1024, 4096, 1);
  k_transpose_cast<<<dim3(1024 / 32, 2048 / 32), dim3(256), 0, stream>>>(W_out, woutT, 2048, 1024, 0);

  // GEMM1: [16384,4096] = xb @ winT^T, K=1024, gated epilogue -> mixed bf16
  k_gemm256<1024, 16, 0><<<dim3(Mdim / 256 * (4096 / 256)), dim3(512), 0, stream>>>(
      xb, winT, b_in, nullptr, mixed, nullptr);

  k_conv<<<dim3(Bdim * (Tdim / 8) * (Sdim / 8) / 256), dim3(256), 0, stream>>>(
      mixed, conv_w, conv_b, hbuf);

  // GEMM2: [16384,1024] = h @ woutT^T, K=2048, residual epilogue -> z fp32
  k_gemm256<2048, 4, 1><<<dim3(Mdim / 256 * (Ddim / 256)), dim3(512), 0, stream>>>(
      hbuf, woutT, b_out, x, nullptr, z);

  k_ln<<<dim3(Mdim), dim3(256), 0, stream>>>(z, gamma, beta, out);
}

// Round 6
// 458.625 us; speedup vs baseline: 1.0250x; 1.0078x over previous
//
#include <hip/hip_runtime.h>
#include <hip/hip_bf16.h>

// StateSpaceMixer MI355X — round 6: strip sched_barrier over-pinning.
// R5 post-mortem: SQ_LDS_BANK_CONFLICT == 1.258e7 for linear/1-bit/2-bit
// swizzles == 4.0 per ds_read_b128 == the structural multi-cycle floor of
// wave64 b128 reads (1024B / 256B-per-clk). Conflicts were never the issue.
// Real suspect: 24 sched_barrier(0)/iter defeating compiler scheduling
// (m141 precedent: −42%). This round keeps ONLY the rule-18 fence
// (sched_barrier after lgkmcnt(0), before MFMA). No other changes.
//
// Workspace layout (<= 172 MiB):
//   [0,64M)    mixed bf16 [16384][2048]   (reused as z fp32 [16384][1024] after conv)
//   [64M,128M) h     bf16 [16384][2048]
//   [128M,160M) xb   bf16 [16384][1024]
//   [160M,168M) W_inT bf16 [4096][1024]  (rows PERMUTED: mixed/gate 16-col interleave)
//   [168M,172M) W_outT bf16 [1024][2048]

#define Bdim 4
#define Tdim 4096
#define Ddim 1024
#define Sdim 2048
#define Mdim (Bdim * Tdim)   // 16384
#define LN_EPS 1e-5f

typedef __bf16 bf16;
typedef __bf16 bf16x8 __attribute__((ext_vector_type(8)));
typedef float f32x4 __attribute__((ext_vector_type(4)));

#define BAR() __builtin_amdgcn_s_barrier()
#define SCHED() __builtin_amdgcn_sched_barrier(0)
#define LGKM0() asm volatile("s_waitcnt lgkmcnt(0)" ::: "memory")
#define VMCNT4() asm volatile("s_waitcnt vmcnt(4)" ::: "memory")
#define VMCNT0() asm volatile("s_waitcnt vmcnt(0)" ::: "memory")

__device__ __forceinline__ void gload_lds16(const bf16* g, bf16* l) {
  __builtin_amdgcn_global_load_lds((const __attribute__((address_space(1))) void*)g,
                                   (__attribute__((address_space(3))) void*)l,
                                   16, 0, 0);
}

__device__ __forceinline__ f32x4 zero4() {
  f32x4 z; z[0] = 0.f; z[1] = 0.f; z[2] = 0.f; z[3] = 0.f; return z;
}

// ---------------- Pass 0a: cast x fp32 -> bf16 ----------------
__global__ __launch_bounds__(256) void k_cast_x(const float* __restrict__ x,
                                                bf16* __restrict__ xb) {
  int gid = blockIdx.x * 256 + threadIdx.x;
  const float4* p = (const float4*)x + (size_t)gid * 2;
  float4 a = p[0], b = p[1];
  bf16x8 o;
  o[0] = (bf16)a.x; o[1] = (bf16)a.y; o[2] = (bf16)a.z; o[3] = (bf16)a.w;
  o[4] = (bf16)b.x; o[5] = (bf16)b.y; o[6] = (bf16)b.z; o[7] = (bf16)b.w;
  ((bf16x8*)xb)[gid] = o;
}

// ---------------- Pass 0b: transpose + cast (+ optional gate-interleave perm) --
__global__ __launch_bounds__(256) void k_transpose_cast(const float* __restrict__ in,
                                                        bf16* __restrict__ out,
                                                        int R, int C, int permmode) {
  __shared__ float tile[32][33];
  int tx = threadIdx.x & 31;
  int ty = threadIdx.x >> 5;           // 0..7
  int r0 = blockIdx.y * 32;
  int c0 = blockIdx.x * 32;
#pragma unroll
  for (int i = 0; i < 4; ++i)
    tile[ty + i * 8][tx] = in[(size_t)(r0 + ty + i * 8) * C + c0 + tx];
  __syncthreads();
#pragma unroll
  for (int i = 0; i < 4; ++i) {
    int oc = c0 + ty + i * 8;
    int pr = oc;
    if (permmode) {
      pr = (oc < 2048) ? ((oc >> 4) * 32 + (oc & 15))
                       : (((oc - 2048) >> 4) * 32 + 16 + (oc & 15));
    }
    out[(size_t)pr * R + r0 + tx] = (bf16)tile[tx][ty + i * 8];
  }
}

// ---------------- 256x256 8-phase GEMM (minimal pinning) ----------
// A [M][KTOT] bf16 row-major, Bg [N][KTOT] bf16 row-major (B^T form).
// LDS per slot (64KB): A0@0, A1@16K, B0@32K, B1@48K; slot1 at +64K.
// Swizzle kept from R5 (2-bit involution, both-sides): correctness-neutral,
// conflict counter shown to be at the b128 floor regardless.
// EPI 0: gated epilogue (permuted-col pairing) -> outb bf16 [M][2048]
// EPI 1: residual epilogue -> outf fp32 [M][1024], xres = x
template<int KTOT, int NTN, int EPI>
__global__ __launch_bounds__(512, 1)
void k_gemm256(const bf16* __restrict__ Ag, const bf16* __restrict__ Bg,
               const float* __restrict__ bias, const float* __restrict__ xres,
               bf16* __restrict__ outb, float* __restrict__ outf) {
  __shared__ __attribute__((aligned(16))) char lds[131072];

  const int tid = threadIdx.x;
  const int w = tid >> 6, lane = tid & 63;
  const int lr = lane & 15, lk = lane >> 4;
  const int wr = w >> 2, wc = w & 3;        // 2 x 4 wave grid

  const int nwg = gridDim.x;
  const int bid = blockIdx.x;
  const int wg = (bid & 7) * (nwg >> 3) + (bid >> 3);   // XCD swizzle (nwg%8==0)
  const int m0 = (wg / NTN) * 256;
  const int n0 = (wg % NTN) * 256;

  // writer-side: linear LDS dest d=lane*16 holds logical offset L = swz(d)
  const int dlin = lane * 16;
  const int lsw = dlin ^ (((dlin >> 7) & 3) << 5);
  const int rw = lsw >> 7;            // row within 8-row chunk
  const int cw = (lsw & 127) >> 1;    // elem col 0..63 (16B aligned)

  // reader-side: addr = row*128 + ((ks*64 + lk*16) ^ ((row&3)<<5))
  const int xmask = (lr & 3) << 5;                 // row&3 == lr&3 for both A,B
  const int arow = lr * 128;
  const int brow = ((wc & 1) * 64 + lr) * 128;
  const char* ldsA = lds + wr * 16384;                 // + slot*65536
  const char* ldsB = lds + 32768 + (wc >> 1) * 16384;  // + slot*65536

  auto stage = [&](const bf16* G, int row0, int kt, int regionByte) {
#pragma unroll
    for (int L = 0; L < 2; ++L) {
      int q = w * 2 + L;
      const bf16* src = G + (size_t)(row0 + q * 8 + rw) * KTOT + kt * 64 + cw;
      gload_lds16(src, (bf16*)(lds + regionByte + q * 1024));
    }
  };
  auto rdA = [&](int s, int mi, int ks) -> bf16x8 {
    return *(const bf16x8*)(ldsA + s * 65536 + mi * 2048 + arow +
                            ((ks * 64 + lk * 16) ^ xmask));
  };
  auto rdB = [&](int s, int nj, int ks) -> bf16x8 {
    return *(const bf16x8*)(ldsB + s * 65536 + nj * 2048 + brow +
                            ((ks * 64 + lk * 16) ^ xmask));
  };

  f32x4 acc[8][4];
#pragma unroll
  for (int i = 0; i < 8; ++i)
#pragma unroll
    for (int j = 0; j < 4; ++j) acc[i][j] = zero4();

  bf16x8 a[4][2], b[4][2];

#define QUAD(rh, ch)                                                                   \
  {                                                                                    \
    _Pragma("unroll")                                                                  \
    for (int mi = 0; mi < 4; ++mi) {                                                   \
      _Pragma("unroll")                                                                \
      for (int nj = 0; nj < 2; ++nj) {                                                 \
        acc[(rh)*4+mi][(ch)*2+nj] = __builtin_amdgcn_mfma_f32_16x16x32_bf16(           \
            a[mi][0], b[(ch)*2+nj][0], acc[(rh)*4+mi][(ch)*2+nj], 0, 0, 0);            \
        acc[(rh)*4+mi][(ch)*2+nj] = __builtin_amdgcn_mfma_f32_16x16x32_bf16(           \
            a[mi][1], b[(ch)*2+nj][1], acc[(rh)*4+mi][(ch)*2+nj], 0, 0, 0);            \
      }                                                                                \
    }                                                                                  \
  }

  const int NI = KTOT / 128;

  // ---- prologue: tile0 all 4 halves, tile1 B halves; allow tile1-B in flight
  stage(Bg, n0,       0, 32768);
  stage(Bg, n0 + 128, 0, 32768 + 16384);
  stage(Ag, m0,       0, 0);
  stage(Ag, m0 + 128, 0, 16384);
  stage(Bg, n0,       1, 65536 + 32768);
  stage(Bg, n0 + 128, 1, 65536 + 32768 + 16384);
  VMCNT4(); BAR();

  for (int i = 0; i < NI; ++i) {
    const int kta2 = 2 * i + 2;   // next even tile -> slot0
    const int ktb  = 2 * i + 1;   // this odd tile  -> slot1
    const bool nl = (i < NI - 1);

    // ---- P1: read A(rh0),B(c0) of even tile (slot0); stage b:A0
#pragma unroll
    for (int mi = 0; mi < 4; ++mi) { a[mi][0] = rdA(0, mi, 0); a[mi][1] = rdA(0, mi, 1); }
#pragma unroll
    for (int nj = 0; nj < 2; ++nj) { b[nj][0] = rdB(0, nj, 0); b[nj][1] = rdB(0, nj, 1); }
    stage(Ag, m0, ktb, 65536);
    asm volatile("s_waitcnt lgkmcnt(8)" ::: "memory");
    BAR(); LGKM0(); SCHED();
    __builtin_amdgcn_s_setprio(1); QUAD(0, 0); __builtin_amdgcn_s_setprio(0);
    BAR();

    // ---- P2: read B(c1); stage b:A1
#pragma unroll
    for (int nj = 0; nj < 2; ++nj) { b[2+nj][0] = rdB(0, 2+nj, 0); b[2+nj][1] = rdB(0, 2+nj, 1); }
    stage(Ag, m0 + 128, ktb, 65536 + 16384);
    BAR(); LGKM0(); SCHED();
    __builtin_amdgcn_s_setprio(1); QUAD(0, 1); __builtin_amdgcn_s_setprio(0);
    BAR();

    // ---- P3: read A(rh1); stage a':B0
#pragma unroll
    for (int mi = 0; mi < 4; ++mi) { a[mi][0] = rdA(0, 4+mi, 0); a[mi][1] = rdA(0, 4+mi, 1); }
    if (nl) stage(Bg, n0, kta2, 32768);
    BAR(); LGKM0(); SCHED();
    __builtin_amdgcn_s_setprio(1); QUAD(1, 0); __builtin_amdgcn_s_setprio(0);
    BAR();

    // ---- P4: stage a':B1; counted vmcnt (odd tile's A-halves guaranteed landed)
    if (nl) stage(Bg, n0 + 128, kta2, 32768 + 16384);
    BAR(); LGKM0(); SCHED();
    __builtin_amdgcn_s_setprio(1); QUAD(1, 1); __builtin_amdgcn_s_setprio(0);
    if (nl) { VMCNT4(); } else { VMCNT0(); }
    BAR();

    // ---- P5: read A(rh0),B(c0) of odd tile (slot1); stage a':A0
#pragma unroll
    for (int mi = 0; mi < 4; ++mi) { a[mi][0] = rdA(1, mi, 0); a[mi][1] = rdA(1, mi, 1); }
#pragma unroll
    for (int nj = 0; nj < 2; ++nj) { b[nj][0] = rdB(1, nj, 0); b[nj][1] = rdB(1, nj, 1); }
    if (nl) stage(Ag, m0, kta2, 0);
    asm volatile("s_waitcnt lgkmcnt(8)" ::: "memory");
    BAR(); LGKM0(); SCHED();
    __builtin_amdgcn_s_setprio(1); QUAD(0, 0); __builtin_amdgcn_s_setprio(0);
    BAR();

    // ---- P6: read B(c1); stage a':A1
#pragma unroll
    for (int nj = 0; nj < 2; ++nj) { b[2+nj][0] = rdB(1, 2+nj, 0); b[2+nj][1] = rdB(1, 2+nj, 1); }
    if (nl) stage(Ag, m0 + 128, kta2, 16384);
    BAR(); LGKM0(); SCHED();
    __builtin_amdgcn_s_setprio(1); QUAD(0, 1); __builtin_amdgcn_s_setprio(0);
    BAR();

    // ---- P7: read A(rh1); stage b':B0
#pragma unroll
    for (int mi = 0; mi < 4; ++mi) { a[mi][0] = rdA(1, 4+mi, 0); a[mi][1] = rdA(1, 4+mi, 1); }
    if (nl) stage(Bg, n0, ktb + 2, 65536 + 32768);
    BAR(); LGKM0(); SCHED();
    __builtin_amdgcn_s_setprio(1); QUAD(1, 0); __builtin_amdgcn_s_setprio(0);
    BAR();

    // ---- P8: stage b':B1; counted vmcnt (next even tile fully landed)
    if (nl) stage(Bg, n0 + 128, ktb + 2, 65536 + 32768 + 16384);
    BAR(); LGKM0(); SCHED();
    __builtin_amdgcn_s_setprio(1); QUAD(1, 1); __builtin_amdgcn_s_setprio(0);
    if (nl) { VMCNT4(); }
    BAR();
  }
#undef QUAD

  // ---- epilogue (no LDS) ----
  if (EPI == 0) {
#pragma unroll
    for (int p = 0; p < 2; ++p) {
      const int g = (n0 + wc * 64 + p * 32) >> 5;
      const int mcol = g * 16 + lr;
      const float bm = bias[mcol];
      const float bg = bias[mcol + 2048];
#pragma unroll
      for (int mi = 0; mi < 8; ++mi)
#pragma unroll
        for (int ii = 0; ii < 4; ++ii) {
          const int row = m0 + wr * 128 + mi * 16 + lk * 4 + ii;
          const float pm = acc[mi][2 * p][ii] + bm;
          const float pg = acc[mi][2 * p + 1][ii] + bg;
          outb[(size_t)row * Sdim + mcol] = (bf16)(pm / (1.0f + __expf(-pg)));
        }
    }
  } else {
#pragma unroll
    for (int nj = 0; nj < 4; ++nj) {
      const int col = n0 + wc * 64 + nj * 16 + lr;
      const float bo = bias[col];
#pragma unroll
      for (int mi = 0; mi < 8; ++mi)
#pragma unroll
        for (int ii = 0; ii < 4; ++ii) {
          const int row = m0 + wr * 128 + mi * 16 + lk * 4 + ii;
          const size_t idx = (size_t)row * Ddim + col;
          outf[idx] = xres[idx] + bo + acc[mi][nj][ii];
        }
    }
  }
}

// ---------------- Pass 2: depthwise causal conv K=4 ----------------
__global__ __launch_bounds__(256) void k_conv(const bf16* __restrict__ mixed,
                                              const float* __restrict__ cw,
                                              const float* __restrict__ cb,
                                              bf16* __restrict__ h) {
  int gid = blockIdx.x * 256 + threadIdx.x;
  int cg = gid & 255;            // channel group (8 ch)
  int tg = (gid >> 8) & 511;     // t group (8 t)
  int bb = gid >> 17;
  int ch0 = cg * 8;
  int t0 = tg * 8;
  const size_t base = ((size_t)bb * Tdim) * Sdim + ch0;

  float4 w4[8];
  float bias[8];
#pragma unroll
  for (int j = 0; j < 8; ++j) {
    w4[j] = ((const float4*)cw)[ch0 + j];
    bias[j] = cb[ch0 + j];
  }

  bf16x8 zv;
#pragma unroll
  for (int j = 0; j < 8; ++j) zv[j] = (bf16)0.0f;

  bf16x8 win[11];
#pragma unroll
  for (int i = 0; i < 11; ++i) {
    int t = t0 - 3 + i;
    win[i] = (t >= 0) ? *(const bf16x8*)(mixed + base + (size_t)t * Sdim) : zv;
  }

#pragma unroll
  for (int i = 0; i < 8; ++i) {
    bf16x8 o;
#pragma unroll
    for (int j = 0; j < 8; ++j) {
      float aa = bias[j]
              + w4[j].x * (float)win[i + 0][j]
              + w4[j].y * (float)win[i + 1][j]
              + w4[j].z * (float)win[i + 2][j]
              + w4[j].w * (float)win[i + 3][j];
      o[j] = (bf16)aa;
    }
    *(bf16x8*)(h + base + (size_t)(t0 + i) * Sdim) = o;
  }
}

// ---------------- Pass 4: LayerNorm over D=1024 ----------------
__global__ __launch_bounds__(256) void k_ln(const float* __restrict__ z,
                                            const float* __restrict__ gamma,
                                            const float* __restrict__ beta,
                                            float* __restrict__ out) {
  int row = blockIdx.x;
  int tid = threadIdx.x;
  const float4* zr = (const float4*)(z + (size_t)row * Ddim);
  float4 v = zr[tid];
  float s = v.x + v.y + v.z + v.w;
  float ss = v.x * v.x + v.y * v.y + v.z * v.z + v.w * v.w;
#pragma unroll
  for (int off = 32; off > 0; off >>= 1) {
    s += __shfl_xor(s, off);
    ss += __shfl_xor(ss, off);
  }
  __shared__ float ps[4], pss[4];
  int wave = tid >> 6, lane = tid & 63;
  if (lane == 0) { ps[wave] = s; pss[wave] = ss; }
  __syncthreads();
  float tots = ps[0] + ps[1] + ps[2] + ps[3];
  float totss = pss[0] + pss[1] + pss[2] + pss[3];
  float mu = tots * (1.0f / (float)Ddim);
  float var = totss * (1.0f / (float)Ddim) - mu * mu;
  float rs = rsqrtf(var + LN_EPS);
  float4 gg = ((const float4*)gamma)[tid];
  float4 bb = ((const float4*)beta)[tid];
  float4 o;
  o.x = (v.x - mu) * rs * gg.x + bb.x;
  o.y = (v.y - mu) * rs * gg.y + bb.y;
  o.z = (v.z - mu) * rs * gg.z + bb.z;
  o.w = (v.w - mu) * rs * gg.w + bb.w;
  ((float4*)(out + (size_t)row * Ddim))[tid] = o;
}

// ---------------- launch ----------------
extern "C" void kernel_launch(void* const* d_in, const int* in_sizes, int n_in,
                              void* d_out, int out_size, void* d_ws, size_t ws_size,
                              hipStream_t stream) {
  const float* x = (const float*)d_in[0];
  const float* W_in = (const float*)d_in[1];
  const float* b_in = (const float*)d_in[2];
  const float* conv_w = (const float*)d_in[3];
  const float* conv_b = (const float*)d_in[4];
  const float* W_out = (const float*)d_in[5];
  const float* b_out = (const float*)d_in[6];
  const float* gamma = (const float*)d_in[7];
  const float* beta = (const float*)d_in[8];
  float* out = (float*)d_out;

  char* ws = (char*)d_ws;
  bf16* mixed = (bf16*)ws;                              // 64 MiB
  bf16* hbuf = (bf16*)(ws + ((size_t)64 << 20));        // 64 MiB
  bf16* xb = (bf16*)(ws + ((size_t)128 << 20));         // 32 MiB
  bf16* winT = (bf16*)(ws + ((size_t)160 << 20));       // 8 MiB (permuted rows)
  bf16* woutT = (bf16*)(ws + ((size_t)168 << 20));      // 4 MiB
  float* z = (float*)mixed;  // mixed dead after conv

  k_cast_x<<<dim3(Mdim * Ddim / 8 / 256), dim3(256), 0, stream>>>(x, xb);
  k_transpose_cast<<<dim3(4096 / 32, 1024 / 32), dim3(256), 0, stream>>>(W_in, winT, 1024, 4096, 1);
  k_transpose_cast<<<dim3(1024 / 32, 2048 / 32), dim3(256), 0, stream>>>(W_out, woutT, 2048, 1024, 0);

  // GEMM1: [16384,4096] = xb @ winT^T, K=1024, gated epilogue -> mixed bf16
  k_gemm256<1024, 16, 0><<<dim3(Mdim / 256 * (4096 / 256)), dim3(512), 0, stream>>>(
      xb, winT, b_in, nullptr, mixed, nullptr);

  k_conv<<<dim3(Bdim * (Tdim / 8) * (Sdim / 8) / 256), dim3(256), 0, stream>>>(
      mixed, conv_w, conv_b, hbuf);

  // GEMM2: [16384,1024] = h @ woutT^T, K=2048, residual epilogue -> z fp32
  k_gemm256<2048, 4, 1><<<dim3(Mdim / 256 * (Ddim / 256)), dim3(512), 0, stream>>>(
      hbuf, woutT, b_out, x, nullptr, z);

  k_ln<<<dim3(Mdim), dim3(256), 0, stream>>>(z, gamma, beta, out);
}

// Round 7
// 450.202 us; speedup vs baseline: 1.0442x; 1.0187x over previous
//
#include <hip/hip_runtime.h>
#include <hip/hip_bf16.h>

// StateSpaceMixer MI355X — round 7: CORRECT 3-bit LDS swizzle.
// R6 model: effective LDS BW ~111 B/cyc/CU = half of achievable -> persistent
// 2x conflict. Root cause: 16B-slot index is byte bits [6:4]; my prior
// swizzles XORed only bits [6:5]/[5], leaving 16 lanes on the 4 even slots.
// Fix (G4 formula, derived): byte' = byte ^ ((row&7)<<4). Reader slot becomes
// (4ks+lk)^(lr&7): all 8 slots covered 2x per 16-lane group (2-way = free).
// Only the swizzle masks change vs R6.
//
// Workspace layout (<= 172 MiB):
//   [0,64M)    mixed bf16 [16384][2048]   (reused as z fp32 [16384][1024] after conv)
//   [64M,128M) h     bf16 [16384][2048]
//   [128M,160M) xb   bf16 [16384][1024]
//   [160M,168M) W_inT bf16 [4096][1024]  (rows PERMUTED: mixed/gate 16-col interleave)
//   [168M,172M) W_outT bf16 [1024][2048]

#define Bdim 4
#define Tdim 4096
#define Ddim 1024
#define Sdim 2048
#define Mdim (Bdim * Tdim)   // 16384
#define LN_EPS 1e-5f

typedef __bf16 bf16;
typedef __bf16 bf16x8 __attribute__((ext_vector_type(8)));
typedef float f32x4 __attribute__((ext_vector_type(4)));

#define BAR() __builtin_amdgcn_s_barrier()
#define SCHED() __builtin_amdgcn_sched_barrier(0)
#define LGKM0() asm volatile("s_waitcnt lgkmcnt(0)" ::: "memory")
#define VMCNT4() asm volatile("s_waitcnt vmcnt(4)" ::: "memory")
#define VMCNT0() asm volatile("s_waitcnt vmcnt(0)" ::: "memory")

__device__ __forceinline__ void gload_lds16(const bf16* g, bf16* l) {
  __builtin_amdgcn_global_load_lds((const __attribute__((address_space(1))) void*)g,
                                   (__attribute__((address_space(3))) void*)l,
                                   16, 0, 0);
}

__device__ __forceinline__ f32x4 zero4() {
  f32x4 z; z[0] = 0.f; z[1] = 0.f; z[2] = 0.f; z[3] = 0.f; return z;
}

// ---------------- Pass 0a: cast x fp32 -> bf16 ----------------
__global__ __launch_bounds__(256) void k_cast_x(const float* __restrict__ x,
                                                bf16* __restrict__ xb) {
  int gid = blockIdx.x * 256 + threadIdx.x;
  const float4* p = (const float4*)x + (size_t)gid * 2;
  float4 a = p[0], b = p[1];
  bf16x8 o;
  o[0] = (bf16)a.x; o[1] = (bf16)a.y; o[2] = (bf16)a.z; o[3] = (bf16)a.w;
  o[4] = (bf16)b.x; o[5] = (bf16)b.y; o[6] = (bf16)b.z; o[7] = (bf16)b.w;
  ((bf16x8*)xb)[gid] = o;
}

// ---------------- Pass 0b: transpose + cast (+ optional gate-interleave perm) --
__global__ __launch_bounds__(256) void k_transpose_cast(const float* __restrict__ in,
                                                        bf16* __restrict__ out,
                                                        int R, int C, int permmode) {
  __shared__ float tile[32][33];
  int tx = threadIdx.x & 31;
  int ty = threadIdx.x >> 5;           // 0..7
  int r0 = blockIdx.y * 32;
  int c0 = blockIdx.x * 32;
#pragma unroll
  for (int i = 0; i < 4; ++i)
    tile[ty + i * 8][tx] = in[(size_t)(r0 + ty + i * 8) * C + c0 + tx];
  __syncthreads();
#pragma unroll
  for (int i = 0; i < 4; ++i) {
    int oc = c0 + ty + i * 8;
    int pr = oc;
    if (permmode) {
      pr = (oc < 2048) ? ((oc >> 4) * 32 + (oc & 15))
                       : (((oc - 2048) >> 4) * 32 + 16 + (oc & 15));
    }
    out[(size_t)pr * R + r0 + tx] = (bf16)tile[tx][ty + i * 8];
  }
}

// ---------------- 256x256 8-phase GEMM (3-bit slot swizzle) ----------
// A [M][KTOT] bf16 row-major, Bg [N][KTOT] bf16 row-major (B^T form).
// LDS per slot (64KB): A0@0, A1@16K, B0@32K, B1@48K; slot1 at +64K.
// Swizzle (involution, both-sides): byte' = byte ^ (((byte>>7)&7)<<4)
//   -> reader slot (4*ks+lk) ^ (row&7): 2 lanes per 16B slot (free).
// EPI 0: gated epilogue (permuted-col pairing) -> outb bf16 [M][2048]
// EPI 1: residual epilogue -> outf fp32 [M][1024], xres = x
template<int KTOT, int NTN, int EPI>
__global__ __launch_bounds__(512, 1)
void k_gemm256(const bf16* __restrict__ Ag, const bf16* __restrict__ Bg,
               const float* __restrict__ bias, const float* __restrict__ xres,
               bf16* __restrict__ outb, float* __restrict__ outf) {
  __shared__ __attribute__((aligned(16))) char lds[131072];

  const int tid = threadIdx.x;
  const int w = tid >> 6, lane = tid & 63;
  const int lr = lane & 15, lk = lane >> 4;
  const int wr = w >> 2, wc = w & 3;        // 2 x 4 wave grid

  const int nwg = gridDim.x;
  const int bid = blockIdx.x;
  const int wg = (bid & 7) * (nwg >> 3) + (bid >> 3);   // XCD swizzle (nwg%8==0)
  const int m0 = (wg / NTN) * 256;
  const int n0 = (wg % NTN) * 256;

  // writer-side: linear LDS dest d=lane*16 holds logical offset L = swz(d)
  const int dlin = lane * 16;
  const int lsw = dlin ^ (((dlin >> 7) & 7) << 4);
  const int rw = lsw >> 7;            // row within 8-row chunk
  const int cw = (lsw & 127) >> 1;    // elem col 0..63 (16B aligned)

  // reader-side: addr = row*128 + ((ks*64 + lk*16) ^ ((row&7)<<4))
  const int xmask = (lr & 7) << 4;                 // row&7 == lr&7 for both A,B
  const int arow = lr * 128;
  const int brow = ((wc & 1) * 64 + lr) * 128;
  const char* ldsA = lds + wr * 16384;                 // + slot*65536
  const char* ldsB = lds + 32768 + (wc >> 1) * 16384;  // + slot*65536

  auto stage = [&](const bf16* G, int row0, int kt, int regionByte) {
#pragma unroll
    for (int L = 0; L < 2; ++L) {
      int q = w * 2 + L;
      const bf16* src = G + (size_t)(row0 + q * 8 + rw) * KTOT + kt * 64 + cw;
      gload_lds16(src, (bf16*)(lds + regionByte + q * 1024));
    }
  };
  auto rdA = [&](int s, int mi, int ks) -> bf16x8 {
    return *(const bf16x8*)(ldsA + s * 65536 + mi * 2048 + arow +
                            ((ks * 64 + lk * 16) ^ xmask));
  };
  auto rdB = [&](int s, int nj, int ks) -> bf16x8 {
    return *(const bf16x8*)(ldsB + s * 65536 + nj * 2048 + brow +
                            ((ks * 64 + lk * 16) ^ xmask));
  };

  f32x4 acc[8][4];
#pragma unroll
  for (int i = 0; i < 8; ++i)
#pragma unroll
    for (int j = 0; j < 4; ++j) acc[i][j] = zero4();

  bf16x8 a[4][2], b[4][2];

#define QUAD(rh, ch)                                                                   \
  {                                                                                    \
    _Pragma("unroll")                                                                  \
    for (int mi = 0; mi < 4; ++mi) {                                                   \
      _Pragma("unroll")                                                                \
      for (int nj = 0; nj < 2; ++nj) {                                                 \
        acc[(rh)*4+mi][(ch)*2+nj] = __builtin_amdgcn_mfma_f32_16x16x32_bf16(           \
            a[mi][0], b[(ch)*2+nj][0], acc[(rh)*4+mi][(ch)*2+nj], 0, 0, 0);            \
        acc[(rh)*4+mi][(ch)*2+nj] = __builtin_amdgcn_mfma_f32_16x16x32_bf16(           \
            a[mi][1], b[(ch)*2+nj][1], acc[(rh)*4+mi][(ch)*2+nj], 0, 0, 0);            \
      }                                                                                \
    }                                                                                  \
  }

  const int NI = KTOT / 128;

  // ---- prologue: tile0 all 4 halves, tile1 B halves; allow tile1-B in flight
  stage(Bg, n0,       0, 32768);
  stage(Bg, n0 + 128, 0, 32768 + 16384);
  stage(Ag, m0,       0, 0);
  stage(Ag, m0 + 128, 0, 16384);
  stage(Bg, n0,       1, 65536 + 32768);
  stage(Bg, n0 + 128, 1, 65536 + 32768 + 16384);
  VMCNT4(); BAR();

  for (int i = 0; i < NI; ++i) {
    const int kta2 = 2 * i + 2;   // next even tile -> slot0
    const int ktb  = 2 * i + 1;   // this odd tile  -> slot1
    const bool nl = (i < NI - 1);

    // ---- P1: read A(rh0),B(c0) of even tile (slot0); stage b:A0
#pragma unroll
    for (int mi = 0; mi < 4; ++mi) { a[mi][0] = rdA(0, mi, 0); a[mi][1] = rdA(0, mi, 1); }
#pragma unroll
    for (int nj = 0; nj < 2; ++nj) { b[nj][0] = rdB(0, nj, 0); b[nj][1] = rdB(0, nj, 1); }
    stage(Ag, m0, ktb, 65536);
    asm volatile("s_waitcnt lgkmcnt(8)" ::: "memory");
    BAR(); LGKM0(); SCHED();
    __builtin_amdgcn_s_setprio(1); QUAD(0, 0); __builtin_amdgcn_s_setprio(0);
    BAR();

    // ---- P2: read B(c1); stage b:A1
#pragma unroll
    for (int nj = 0; nj < 2; ++nj) { b[2+nj][0] = rdB(0, 2+nj, 0); b[2+nj][1] = rdB(0, 2+nj, 1); }
    stage(Ag, m0 + 128, ktb, 65536 + 16384);
    BAR(); LGKM0(); SCHED();
    __builtin_amdgcn_s_setprio(1); QUAD(0, 1); __builtin_amdgcn_s_setprio(0);
    BAR();

    // ---- P3: read A(rh1); stage a':B0
#pragma unroll
    for (int mi = 0; mi < 4; ++mi) { a[mi][0] = rdA(0, 4+mi, 0); a[mi][1] = rdA(0, 4+mi, 1); }
    if (nl) stage(Bg, n0, kta2, 32768);
    BAR(); LGKM0(); SCHED();
    __builtin_amdgcn_s_setprio(1); QUAD(1, 0); __builtin_amdgcn_s_setprio(0);
    BAR();

    // ---- P4: stage a':B1; counted vmcnt (odd tile's A-halves guaranteed landed)
    if (nl) stage(Bg, n0 + 128, kta2, 32768 + 16384);
    BAR(); LGKM0(); SCHED();
    __builtin_amdgcn_s_setprio(1); QUAD(1, 1); __builtin_amdgcn_s_setprio(0);
    if (nl) { VMCNT4(); } else { VMCNT0(); }
    BAR();

    // ---- P5: read A(rh0),B(c0) of odd tile (slot1); stage a':A0
#pragma unroll
    for (int mi = 0; mi < 4; ++mi) { a[mi][0] = rdA(1, mi, 0); a[mi][1] = rdA(1, mi, 1); }
#pragma unroll
    for (int nj = 0; nj < 2; ++nj) { b[nj][0] = rdB(1, nj, 0); b[nj][1] = rdB(1, nj, 1); }
    if (nl) stage(Ag, m0, kta2, 0);
    asm volatile("s_waitcnt lgkmcnt(8)" ::: "memory");
    BAR(); LGKM0(); SCHED();
    __builtin_amdgcn_s_setprio(1); QUAD(0, 0); __builtin_amdgcn_s_setprio(0);
    BAR();

    // ---- P6: read B(c1); stage a':A1
#pragma unroll
    for (int nj = 0; nj < 2; ++nj) { b[2+nj][0] = rdB(1, 2+nj, 0); b[2+nj][1] = rdB(1, 2+nj, 1); }
    if (nl) stage(Ag, m0 + 128, kta2, 16384);
    BAR(); LGKM0(); SCHED();
    __builtin_amdgcn_s_setprio(1); QUAD(0, 1); __builtin_amdgcn_s_setprio(0);
    BAR();

    // ---- P7: read A(rh1); stage b':B0
#pragma unroll
    for (int mi = 0; mi < 4; ++mi) { a[mi][0] = rdA(1, 4+mi, 0); a[mi][1] = rdA(1, 4+mi, 1); }
    if (nl) stage(Bg, n0, ktb + 2, 65536 + 32768);
    BAR(); LGKM0(); SCHED();
    __builtin_amdgcn_s_setprio(1); QUAD(1, 0); __builtin_amdgcn_s_setprio(0);
    BAR();

    // ---- P8: stage b':B1; counted vmcnt (next even tile fully landed)
    if (nl) stage(Bg, n0 + 128, ktb + 2, 65536 + 32768 + 16384);
    BAR(); LGKM0(); SCHED();
    __builtin_amdgcn_s_setprio(1); QUAD(1, 1); __builtin_amdgcn_s_setprio(0);
    if (nl) { VMCNT4(); }
    BAR();
  }
#undef QUAD

  // ---- epilogue (no LDS) ----
  if (EPI == 0) {
#pragma unroll
    for (int p = 0; p < 2; ++p) {
      const int g = (n0 + wc * 64 + p * 32) >> 5;
      const int mcol = g * 16 + lr;
      const float bm = bias[mcol];
      const float bg = bias[mcol + 2048];
#pragma unroll
      for (int mi = 0; mi < 8; ++mi)
#pragma unroll
        for (int ii = 0; ii < 4; ++ii) {
          const int row = m0 + wr * 128 + mi * 16 + lk * 4 + ii;
          const float pm = acc[mi][2 * p][ii] + bm;
          const float pg = acc[mi][2 * p + 1][ii] + bg;
          outb[(size_t)row * Sdim + mcol] = (bf16)(pm / (1.0f + __expf(-pg)));
        }
    }
  } else {
#pragma unroll
    for (int nj = 0; nj < 4; ++nj) {
      const int col = n0 + wc * 64 + nj * 16 + lr;
      const float bo = bias[col];
#pragma unroll
      for (int mi = 0; mi < 8; ++mi)
#pragma unroll
        for (int ii = 0; ii < 4; ++ii) {
          const int row = m0 + wr * 128 + mi * 16 + lk * 4 + ii;
          const size_t idx = (size_t)row * Ddim + col;
          outf[idx] = xres[idx] + bo + acc[mi][nj][ii];
        }
    }
  }
}

// ---------------- Pass 2: depthwise causal conv K=4 ----------------
__global__ __launch_bounds__(256) void k_conv(const bf16* __restrict__ mixed,
                                              const float* __restrict__ cw,
                                              const float* __restrict__ cb,
                                              bf16* __restrict__ h) {
  int gid = blockIdx.x * 256 + threadIdx.x;
  int cg = gid & 255;            // channel group (8 ch)
  int tg = (gid >> 8) & 511;     // t group (8 t)
  int bb = gid >> 17;
  int ch0 = cg * 8;
  int t0 = tg * 8;
  const size_t base = ((size_t)bb * Tdim) * Sdim + ch0;

  float4 w4[8];
  float bias[8];
#pragma unroll
  for (int j = 0; j < 8; ++j) {
    w4[j] = ((const float4*)cw)[ch0 + j];
    bias[j] = cb[ch0 + j];
  }

  bf16x8 zv;
#pragma unroll
  for (int j = 0; j < 8; ++j) zv[j] = (bf16)0.0f;

  bf16x8 win[11];
#pragma unroll
  for (int i = 0; i < 11; ++i) {
    int t = t0 - 3 + i;
    win[i] = (t >= 0) ? *(const bf16x8*)(mixed + base + (size_t)t * Sdim) : zv;
  }

#pragma unroll
  for (int i = 0; i < 8; ++i) {
    bf16x8 o;
#pragma unroll
    for (int j = 0; j < 8; ++j) {
      float aa = bias[j]
              + w4[j].x * (float)win[i + 0][j]
              + w4[j].y * (float)win[i + 1][j]
              + w4[j].z * (float)win[i + 2][j]
              + w4[j].w * (float)win[i + 3][j];
      o[j] = (bf16)aa;
    }
    *(bf16x8*)(h + base + (size_t)(t0 + i) * Sdim) = o;
  }
}

// ---------------- Pass 4: LayerNorm over D=1024 ----------------
__global__ __launch_bounds__(256) void k_ln(const float* __restrict__ z,
                                            const float* __restrict__ gamma,
                                            const float* __restrict__ beta,
                                            float* __restrict__ out) {
  int row = blockIdx.x;
  int tid = threadIdx.x;
  const float4* zr = (const float4*)(z + (size_t)row * Ddim);
  float4 v = zr[tid];
  float s = v.x + v.y + v.z + v.w;
  float ss = v.x * v.x + v.y * v.y + v.z * v.z + v.w * v.w;
#pragma unroll
  for (int off = 32; off > 0; off >>= 1) {
    s += __shfl_xor(s, off);
    ss += __shfl_xor(ss, off);
  }
  __shared__ float ps[4], pss[4];
  int wave = tid >> 6, lane = tid & 63;
  if (lane == 0) { ps[wave] = s; pss[wave] = ss; }
  __syncthreads();
  float tots = ps[0] + ps[1] + ps[2] + ps[3];
  float totss = pss[0] + pss[1] + pss[2] + pss[3];
  float mu = tots * (1.0f / (float)Ddim);
  float var = totss * (1.0f / (float)Ddim) - mu * mu;
  float rs = rsqrtf(var + LN_EPS);
  float4 gg = ((const float4*)gamma)[tid];
  float4 bb = ((const float4*)beta)[tid];
  float4 o;
  o.x = (v.x - mu) * rs * gg.x + bb.x;
  o.y = (v.y - mu) * rs * gg.y + bb.y;
  o.z = (v.z - mu) * rs * gg.z + bb.z;
  o.w = (v.w - mu) * rs * gg.w + bb.w;
  ((float4*)(out + (size_t)row * Ddim))[tid] = o;
}

// ---------------- launch ----------------
extern "C" void kernel_launch(void* const* d_in, const int* in_sizes, int n_in,
                              void* d_out, int out_size, void* d_ws, size_t ws_size,
                              hipStream_t stream) {
  const float* x = (const float*)d_in[0];
  const float* W_in = (const float*)d_in[1];
  const float* b_in = (const float*)d_in[2];
  const float* conv_w = (const float*)d_in[3];
  const float* conv_b = (const float*)d_in[4];
  const float* W_out = (const float*)d_in[5];
  const float* b_out = (const float*)d_in[6];
  const float* gamma = (const float*)d_in[7];
  const float* beta = (const float*)d_in[8];
  float* out = (float*)d_out;

  char* ws = (char*)d_ws;
  bf16* mixed = (bf16*)ws;                              // 64 MiB
  bf16* hbuf = (bf16*)(ws + ((size_t)64 << 20));        // 64 MiB
  bf16* xb = (bf16*)(ws + ((size_t)128 << 20));         // 32 MiB
  bf16* winT = (bf16*)(ws + ((size_t)160 << 20));       // 8 MiB (permuted rows)
  bf16* woutT = (bf16*)(ws + ((size_t)168 << 20));      // 4 MiB
  float* z = (float*)mixed;  // mixed dead after conv

  k_cast_x<<<dim3(Mdim * Ddim / 8 / 256), dim3(256), 0, stream>>>(x, xb);
  k_transpose_cast<<<dim3(4096 / 32, 1024 / 32), dim3(256), 0, stream>>>(W_in, winT, 1024, 4096, 1);
  k_transpose_cast<<<dim3(1024 / 32, 2048 / 32), dim3(256), 0, stream>>>(W_out, woutT, 2048, 1024, 0);

  // GEMM1: [16384,4096] = xb @ winT^T, K=1024, gated epilogue -> mixed bf16
  k_gemm256<1024, 16, 0><<<dim3(Mdim / 256 * (4096 / 256)), dim3(512), 0, stream>>>(
      xb, winT, b_in, nullptr, mixed, nullptr);

  k_conv<<<dim3(Bdim * (Tdim / 8) * (Sdim / 8) / 256), dim3(256), 0, stream>>>(
      mixed, conv_w, conv_b, hbuf);

  // GEMM2: [16384,1024] = h @ woutT^T, K=2048, residual epilogue -> z fp32
  k_gemm256<2048, 4, 1><<<dim3(Mdim / 256 * (Ddim / 256)), dim3(512), 0, stream>>>(
      hbuf, woutT, b_out, x, nullptr, z);

  k_ln<<<dim3(Mdim), dim3(256), 0, stream>>>(z, gamma, beta, out);
}